// Round 8
// baseline (2275.095 us; speedup 1.0000x reference)
//
#include <hip/hip_runtime.h>
#include <hip/hip_bf16.h>
#include <cstdint>

#define EPS 1e-5

typedef __attribute__((ext_vector_type(4))) int int32x4;

// ---------------------------------------------------------------- async global->LDS
__device__ __forceinline__ void gload(const char* g, char* l) {
  __builtin_amdgcn_global_load_lds(
      (const __attribute__((address_space(1))) unsigned int*)g,
      (__attribute__((address_space(3))) unsigned int*)l, 16, 0, 0);
}

// =============================================================================
// numpy-exact fp32 pairwise mean of |w| (see round 2-4 notes).
// =============================================================================
__device__ inline float np_leaf_abs(const float* __restrict__ a, int n) {
  float r[8];
  #pragma unroll
  for (int j = 0; j < 8; j++) r[j] = fabsf(a[j]);
  for (int i = 8; i < n; i += 8) {
    #pragma unroll
    for (int j = 0; j < 8; j++) r[j] += fabsf(a[i + j]);
  }
  return ((r[0] + r[1]) + (r[2] + r[3])) + ((r[4] + r[5]) + (r[6] + r[7]));
}

__global__ __launch_bounds__(256) void np_blocksums(
    const float* __restrict__ w, float* __restrict__ bs) {
  int b = blockIdx.x * 256 + threadIdx.x;   // [0, 131072)
  const float* a = w + (long)b * 344;
  float s0 = np_leaf_abs(a, 80);
  float s1 = np_leaf_abs(a + 80, 88);
  float s2 = np_leaf_abs(a + 168, 88);
  float s3 = np_leaf_abs(a + 256, 88);
  bs[b] = (s0 + s1) + (s2 + s3);
}

__global__ __launch_bounds__(256) void np_tree_partial(
    const float* __restrict__ bs, float* __restrict__ part) {
  __shared__ float sh[256];
  int t = threadIdx.x;
  const float* a = bs + (long)blockIdx.x * 512;
  sh[t] = a[2 * t] + a[2 * t + 1];
  __syncthreads();
  for (int n = 128; n >= 1; n >>= 1) {
    float x = 0.f;
    if (t < n) x = sh[2 * t] + sh[2 * t + 1];
    __syncthreads();
    if (t < n) sh[t] = x;
    __syncthreads();
  }
  if (t == 0) part[blockIdx.x] = sh[0];
}

__global__ __launch_bounds__(128) void np_tree_final(
    const float* __restrict__ part, float* __restrict__ out) {
  __shared__ float sh[128];
  int t = threadIdx.x;
  sh[t] = part[2 * t] + part[2 * t + 1];
  __syncthreads();
  for (int n = 64; n >= 1; n >>= 1) {
    float x = 0.f;
    if (t < n) x = sh[2 * t] + sh[2 * t + 1];
    __syncthreads();
    if (t < n) sh[t] = x;
    __syncthreads();
  }
  if (t == 0) out[0] = sh[0] / 45088768.0f;
}

// ------------------------------------------------------- weight ternarize
__global__ __launch_bounds__(256) void quant_w(
    const float* __restrict__ w, const float* __restrict__ mean_ptr,
    char* __restrict__ q, long n4) {
  float scale = 1.0f / fmaxf(*mean_ptr, 1e-5f);
  long i = (long)blockIdx.x * blockDim.x + threadIdx.x;
  long stride = (long)gridDim.x * blockDim.x;
  const float4* w4 = (const float4*)w;
  char4* q4 = (char4*)q;
  for (; i < n4; i += stride) {
    float4 v = w4[i];
    char4 c;
    c.x = (char)(int)fminf(1.f, fmaxf(-1.f, rintf(v.x * scale)));
    c.y = (char)(int)fminf(1.f, fmaxf(-1.f, rintf(v.y * scale)));
    c.z = (char)(int)fminf(1.f, fmaxf(-1.f, rintf(v.z * scale)));
    c.w = (char)(int)fminf(1.f, fmaxf(-1.f, rintf(v.w * scale)));
    q4[i] = c;
  }
}

// w_down ternarize with boundary-midpoint hedging (see round 3/4 notes).
#define CORR_MAX 1024
#define WIN 1e-6f

__global__ __launch_bounds__(256) void quant_w_down(
    const float* __restrict__ w, const float* __restrict__ mean_ptr,
    char* __restrict__ q, int* __restrict__ cnt,
    int* __restrict__ ck, float* __restrict__ cv) {
  float scale = 1.0f / fmaxf(*mean_ptr, 1e-5f);
  long i0 = ((long)blockIdx.x * blockDim.x + threadIdx.x) * 4;
  long stride = (long)gridDim.x * blockDim.x * 4;
  for (long i = i0; i < 4096L * 11008L; i += stride) {
    char4 c;
    #pragma unroll
    for (int j = 0; j < 4; j++) {
      float t = w[i + j] * scale;
      float qv = fminf(1.f, fmaxf(-1.f, rintf(t)));
      if (fabsf(fabsf(t) - 0.5f) < WIN) {
        qv = 0.f;
        int idx = atomicAdd(cnt, 1);
        if (idx < CORR_MAX) {
          ck[idx] = (int)(i + j);                 // flat n*11008+k
          cv[idx] = t > 0.f ? 0.5f : -0.5f;
        }
      }
      ((char*)&c)[j] = (char)(int)qv;
    }
    *(char4*)(q + i) = c;
  }
}

__global__ void zero_cnt(int* cnt) { *cnt = 0; }

__global__ __launch_bounds__(64) void apply_corr(
    const int* __restrict__ cnt, const int* __restrict__ ck,
    const float* __restrict__ cv, const char* __restrict__ qh,
    const float* __restrict__ fh, const float* __restrict__ meanw,
    float* __restrict__ out) {
  int r = blockIdx.x * 64 + threadIdx.x;  // 8192 rows
  float fwd = fmaxf(meanw[2], 1e-5f);
  int n = *cnt; if (n > CORR_MAX) n = CORR_MAX;
  float fr = fh[r] * fwd;
  for (int i = 0; i < n; i++) {
    int flat = ck[i];
    int nn = flat / 11008, kk = flat % 11008;
    float qv = (float)qh[(long)r * 11008 + kk];
    out[(long)r * 4096 + nn] += cv[i] * qv * fr;
  }
}

// ---------------------------------------------------------------- reductions
__device__ inline void block_reduce_sum_max_d(double& s, float& m) {
  #pragma unroll
  for (int off = 1; off < 64; off <<= 1) {
    s += __shfl_xor(s, off, 64);
    m = fmaxf(m, __shfl_xor(m, off, 64));
  }
  __shared__ double ssh[4];
  __shared__ float msh[4];
  int wv = threadIdx.x >> 6;
  if ((threadIdx.x & 63) == 0) { ssh[wv] = s; msh[wv] = m; }
  __syncthreads();
  s = (ssh[0] + ssh[1]) + (ssh[2] + ssh[3]);
  m = fmaxf(fmaxf(msh[0], msh[1]), fmaxf(msh[2], msh[3]));
}

// ------------------------------------------------------- activation quant
__device__ inline char quant1d(float x, double rn, double s) {
  double t = (double)x * rn;
  double q = rint(t * s);
  q = fmin(127.0, fmax(-128.0, q));
  return (char)(int)q;
}

__global__ __launch_bounds__(256) void act_quant_x(
    const float* __restrict__ x, char* __restrict__ qx, float* __restrict__ fx) {
  const int row = blockIdx.x;
  const float4* xr = (const float4*)(x + (long)row * 4096);
  float4 v[4];
  double ss = 0.0;
  float am = 0.f;
  #pragma unroll
  for (int i = 0; i < 4; i++) {
    v[i] = xr[i * 256 + threadIdx.x];
    ss += ((double)v[i].x * v[i].x + (double)v[i].y * v[i].y) +
          ((double)v[i].z * v[i].z + (double)v[i].w * v[i].w);
    am = fmaxf(am, fmaxf(fmaxf(fabsf(v[i].x), fabsf(v[i].y)),
                         fmaxf(fabsf(v[i].z), fabsf(v[i].w))));
  }
  block_reduce_sum_max_d(ss, am);
  double rn = 1.0 / sqrt(ss / 4096.0 + EPS);
  double den = fmax((double)am * rn, EPS);
  double s = 127.0 / den;
  if (threadIdx.x == 0) fx[row] = (float)(den / 127.0);
  char4* qr = (char4*)(qx + (long)row * 4096);
  #pragma unroll
  for (int i = 0; i < 4; i++) {
    char4 c;
    c.x = quant1d(v[i].x, rn, s);
    c.y = quant1d(v[i].y, rn, s);
    c.z = quant1d(v[i].z, rn, s);
    c.w = quant1d(v[i].w, rn, s);
    qr[i * 256 + threadIdx.x] = c;
  }
}

__global__ __launch_bounds__(256) void act_quant_h(
    const float* __restrict__ h, char* __restrict__ qh, float* __restrict__ fh) {
  const long row = blockIdx.x;
  const float4* hr = (const float4*)(h + row * 11008);
  double ss = 0.0;
  float am = 0.f;
  for (int i = threadIdx.x; i < 2752; i += 256) {
    float4 v = hr[i];
    ss += ((double)v.x * v.x + (double)v.y * v.y) +
          ((double)v.z * v.z + (double)v.w * v.w);
    am = fmaxf(am, fmaxf(fmaxf(fabsf(v.x), fabsf(v.y)),
                         fmaxf(fabsf(v.z), fabsf(v.w))));
  }
  block_reduce_sum_max_d(ss, am);
  double rn = 1.0 / sqrt(ss / 11008.0 + EPS);
  double den = fmax((double)am * rn, EPS);
  double s = 127.0 / den;
  if (threadIdx.x == 0) fh[row] = (float)(den / 127.0);
  char4* qr = (char4*)(qh + row * 11008);
  for (int i = threadIdx.x; i < 2752; i += 256) {
    float4 v = hr[i];
    char4 c;
    c.x = quant1d(v.x, rn, s);
    c.y = quant1d(v.y, rn, s);
    c.z = quant1d(v.z, rn, s);
    c.w = quant1d(v.w, rn, s);
    qr[i] = c;
  }
}

// =============================================================================
// GEMMs: mfma_i32_16x16x64_i8, 3-deep global_load_lds pipeline with COUNTED
// vmcnt (never drain to 0 in steady state) + raw s_barrier. Stage k is issued
// 2 iterations ahead of use. Rotation swizzle (conflict-free, verified r5):
// LDS slot (c + (row>>1))&3 realized by pre-rotating the per-lane GLOBAL src
// column; LDS stays linear for global_load_lds. XCD-bijective block swizzle.
//
// gateup: 128x256 tile, 8 waves (2m x 4n), per-wave 64x64 per matrix,
//         LDS 3*(8K+16K+16K)=120KB, 5 loads/stage/thread -> vmcnt(5).
// down:   256x256 tile, 8 waves (2m x 4n), per-wave 128x64,
//         LDS 3*(16K+16K)=96KB, 4 loads/stage/thread -> vmcnt(4).
// =============================================================================

__global__ __launch_bounds__(512, 2) void gemm_gateup(
    const char* __restrict__ qx, const char* __restrict__ qwg, const char* __restrict__ qwu,
    const float* __restrict__ meanw, const float* __restrict__ fx, float* __restrict__ h) {
  __shared__ __align__(16) char As[3][8192];
  __shared__ __align__(16) char Bgs[3][16384];
  __shared__ __align__(16) char Bus[3][16384];
  const int t = threadIdx.x;
  const int lane = t & 63;
  const int wv = t >> 6;                       // 0..7
  const int bid = blockIdx.x;                  // 2752 = 8 * 344
  const int swz = (bid & 7) * 344 + (bid >> 3);
  const int m0 = (swz & 63) * 128;
  const int n0 = (swz >> 6) * 256;
  const int wm = (wv >> 2) * 64;               // 0,64
  const int wn = (wv & 3) * 64;                // 0..192

  const int rowin = lane >> 2;
  const int gcol = (((lane & 3) - ((lane >> 3) & 3)) & 3) * 16;
  const int slot = ((((lane >> 4) + ((lane >> 1) & 3)) & 3) << 4);
  const int lrow = (lane & 15) * 64;

  const char* gA = qx  + (long)(m0 + wv * 16 + rowin) * 4096 + gcol;
  const char* gG = qwg + (long)(n0 + wv * 32 + rowin) * 4096 + gcol;
  const char* gU = qwu + (long)(n0 + wv * 32 + rowin) * 4096 + gcol;
  const long R16 = 16L * 4096;

  int32x4 accg[4][4] = {};
  int32x4 accu[4][4] = {};

  #define STAGE_GU(pb, k0)                                 \
    do {                                                   \
      gload(gA + (k0),       &As [pb][wv * 1024]);         \
      gload(gG + (k0),       &Bgs[pb][wv * 2048]);         \
      gload(gG + (k0) + R16, &Bgs[pb][wv * 2048 + 1024]);  \
      gload(gU + (k0),       &Bus[pb][wv * 2048]);         \
      gload(gU + (k0) + R16, &Bus[pb][wv * 2048 + 1024]);  \
    } while (0)

  STAGE_GU(0, 0);
  STAGE_GU(1, 64);
  for (int ks = 0; ks < 64; ++ks) {
    const int pb = ks % 3;
    // wait for stage ks only (keep stage ks+1 in flight), then barrier
    if (ks < 63) asm volatile("s_waitcnt vmcnt(5)\n\ts_barrier" ::: "memory");
    else         asm volatile("s_waitcnt vmcnt(0)\n\ts_barrier" ::: "memory");
    if (ks + 2 < 64) STAGE_GU((ks + 2) % 3, (ks + 2) * 64);
    const char* ab = &As [pb][0] + wm * 64 + lrow + slot;
    const char* gb = &Bgs[pb][0] + wn * 64 + lrow + slot;
    const char* ub = &Bus[pb][0] + wn * 64 + lrow + slot;
    int32x4 a[4];
    #pragma unroll
    for (int m = 0; m < 4; m++) a[m] = *(const int32x4*)(ab + m * 1024);
    #pragma unroll
    for (int n = 0; n < 4; n++) {
      int32x4 bg = *(const int32x4*)(gb + n * 1024);
      int32x4 bu = *(const int32x4*)(ub + n * 1024);
      #pragma unroll
      for (int m = 0; m < 4; m++) {
        accg[m][n] = __builtin_amdgcn_mfma_i32_16x16x64_i8(a[m], bg, accg[m][n], 0, 0, 0);
        accu[m][n] = __builtin_amdgcn_mfma_i32_16x16x64_i8(a[m], bu, accu[m][n], 0, 0, 0);
      }
    }
  }
  #undef STAGE_GU

  float fwg = fmaxf(meanw[0], 1e-5f);
  float fwu = fmaxf(meanw[1], 1e-5f);
  const int rgrp = lane >> 4;
  const int cidx = lane & 15;
  #pragma unroll
  for (int m = 0; m < 4; m++) {
    #pragma unroll
    for (int r = 0; r < 4; r++) {
      int grow = m0 + wm + m * 16 + rgrp * 4 + r;
      float fxr = fx[grow];
      float sg = fxr * fwg, su = fxr * fwu;
      #pragma unroll
      for (int n = 0; n < 4; n++) {
        float g = (float)accg[m][n][r] * sg;
        float u = (float)accu[m][n][r] * su;
        float hv = g / (1.f + expf(-g)) * u;
        h[(long)grow * 11008 + (n0 + wn + n * 16 + cidx)] = hv;
      }
    }
  }
}

__global__ __launch_bounds__(512, 2) void gemm_down(
    const char* __restrict__ qh, const char* __restrict__ qwd,
    const float* __restrict__ mean_wd, const float* __restrict__ fh,
    float* __restrict__ out) {
  __shared__ __align__(16) char As[3][16384];
  __shared__ __align__(16) char Bs[3][16384];
  const int t = threadIdx.x;
  const int lane = t & 63;
  const int wv = t >> 6;
  const int bid = blockIdx.x;                  // 512 = 8 * 64
  const int swz = (bid & 7) * 64 + (bid >> 3);
  const int m0 = (swz & 31) * 256;
  const int n0 = (swz >> 5) * 256;
  const int wm = (wv >> 2) * 128;              // 0,128
  const int wn = (wv & 3) * 64;                // 0..192

  const int rowin = lane >> 2;
  const int gcol = (((lane & 3) - ((lane >> 3) & 3)) & 3) * 16;
  const int slot = ((((lane >> 4) + ((lane >> 1) & 3)) & 3) << 4);
  const int lrow = (lane & 15) * 64;

  const char* gA = qh  + (long)(m0 + wv * 32 + rowin) * 11008 + gcol;
  const char* gB = qwd + (long)(n0 + wv * 32 + rowin) * 11008 + gcol;
  const long R16 = 16L * 11008;

  int32x4 acc[8][4] = {};

  #define STAGE_DN(pb, k0)                                \
    do {                                                  \
      gload(gA + (k0),       &As[pb][wv * 2048]);         \
      gload(gA + (k0) + R16, &As[pb][wv * 2048 + 1024]);  \
      gload(gB + (k0),       &Bs[pb][wv * 2048]);         \
      gload(gB + (k0) + R16, &Bs[pb][wv * 2048 + 1024]);  \
    } while (0)

  STAGE_DN(0, 0);
  STAGE_DN(1, 64);
  for (int ks = 0; ks < 172; ++ks) {
    const int pb = ks % 3;
    if (ks < 171) asm volatile("s_waitcnt vmcnt(4)\n\ts_barrier" ::: "memory");
    else          asm volatile("s_waitcnt vmcnt(0)\n\ts_barrier" ::: "memory");
    if (ks + 2 < 172) STAGE_DN((ks + 2) % 3, (ks + 2) * 64);
    const char* ab = &As[pb][0] + wm * 64 + lrow + slot;
    const char* bb = &Bs[pb][0] + wn * 64 + lrow + slot;
    int32x4 a[8];
    #pragma unroll
    for (int m = 0; m < 8; m++) a[m] = *(const int32x4*)(ab + m * 1024);
    #pragma unroll
    for (int n = 0; n < 4; n++) {
      int32x4 b = *(const int32x4*)(bb + n * 1024);
      #pragma unroll
      for (int m = 0; m < 8; m++)
        acc[m][n] = __builtin_amdgcn_mfma_i32_16x16x64_i8(a[m], b, acc[m][n], 0, 0, 0);
    }
  }
  #undef STAGE_DN

  float fwd = fmaxf(mean_wd[0], 1e-5f);
  const int rgrp = lane >> 4;
  const int cidx = lane & 15;
  #pragma unroll
  for (int m = 0; m < 8; m++) {
    #pragma unroll
    for (int r = 0; r < 4; r++) {
      int grow = m0 + wm + m * 16 + rgrp * 4 + r;
      float f = fh[grow] * fwd;
      #pragma unroll
      for (int n = 0; n < 4; n++) {
        out[(long)grow * 4096 + (n0 + wn + n * 16 + cidx)] =
            (float)acc[m][n][r] * f;
      }
    }
  }
}

// ---------------------------------------------------------------- launch
extern "C" void kernel_launch(void* const* d_in, const int* in_sizes, int n_in,
                              void* d_out, int out_size, void* d_ws, size_t ws_size,
                              hipStream_t stream) {
  const float* x      = (const float*)d_in[0];
  const float* w_gate = (const float*)d_in[1];
  const float* w_up   = (const float*)d_in[2];
  const float* w_down = (const float*)d_in[3];
  float* out = (float*)d_out;

  const long NW = 11008L * 4096L;     // 45088768 per weight
  const long NX = 8192L * 4096L;      // 33554432
  const long NH = 8192L * 11008L;     // 90177536

  char* ws  = (char*)d_ws;
  char* qwg = ws;
  char* qwu = qwg + NW;
  char* qwd = qwu + NW;
  char* qx  = qwd + NW;
  char* qh  = qx + NX;
  float* h  = (float*)(qh + NH);
  float* fx = h + NH;                 // 8192 floats
  float* fh = fx + 8192;              // 8192 floats
  float* meanw = fh + 8192;           // [0]=gate [1]=up [2]=down (+pad)
  float* bs    = meanw + 4;           // 131072 floats (reused per matrix)
  float* tmp   = bs + 131072;         // 256 floats used
  int*   ccnt  = (int*)(tmp + 65536);
  int*   ck    = ccnt + 4;            // CORR_MAX ints
  float* cv    = (float*)(ck + CORR_MAX);

  zero_cnt<<<1, 1, 0, stream>>>(ccnt);

  // numpy-style fp32 pairwise means (pairing bit-identical to sequential tree)
  np_blocksums<<<512, 256, 0, stream>>>(w_gate, bs);
  np_tree_partial<<<256, 256, 0, stream>>>(bs, tmp);
  np_tree_final<<<1, 128, 0, stream>>>(tmp, meanw + 0);
  np_blocksums<<<512, 256, 0, stream>>>(w_up, bs);
  np_tree_partial<<<256, 256, 0, stream>>>(bs, tmp);
  np_tree_final<<<1, 128, 0, stream>>>(tmp, meanw + 1);
  np_blocksums<<<512, 256, 0, stream>>>(w_down, bs);
  np_tree_partial<<<256, 256, 0, stream>>>(bs, tmp);
  np_tree_final<<<1, 128, 0, stream>>>(tmp, meanw + 2);

  quant_w<<<4096, 256, 0, stream>>>(w_gate, meanw + 0, qwg, NW / 4);
  quant_w<<<4096, 256, 0, stream>>>(w_up,   meanw + 1, qwu, NW / 4);
  quant_w_down<<<4096, 256, 0, stream>>>(w_down, meanw + 2, qwd, ccnt, ck, cv);

  act_quant_x<<<8192, 256, 0, stream>>>(x, qx, fx);

  gemm_gateup<<<2752, 512, 0, stream>>>(qx, qwg, qwu, meanw, fx, h);

  act_quant_h<<<8192, 256, 0, stream>>>(h, qh, fh);

  gemm_down<<<512, 512, 0, stream>>>(qh, qwd, meanw + 2, fh, out);

  apply_corr<<<128, 64, 0, stream>>>(ccnt, ck, cv, qh, fh, meanw, out);
}

// Round 9
// 1881.007 us; speedup vs baseline: 1.2095x; 1.2095x over previous
//
#include <hip/hip_runtime.h>
#include <hip/hip_bf16.h>
#include <cstdint>

#define EPS 1e-5

typedef __attribute__((ext_vector_type(4))) int int32x4;

// ---------------------------------------------------------------- async global->LDS
__device__ __forceinline__ void gload(const char* g, char* l) {
  __builtin_amdgcn_global_load_lds(
      (const __attribute__((address_space(1))) unsigned int*)g,
      (__attribute__((address_space(3))) unsigned int*)l, 16, 0, 0);
}

// =============================================================================
// numpy-exact fp32 pairwise mean of |w| (see round 2-4 notes).
// =============================================================================
__device__ inline float np_leaf_abs(const float* __restrict__ a, int n) {
  float r[8];
  #pragma unroll
  for (int j = 0; j < 8; j++) r[j] = fabsf(a[j]);
  for (int i = 8; i < n; i += 8) {
    #pragma unroll
    for (int j = 0; j < 8; j++) r[j] += fabsf(a[i + j]);
  }
  return ((r[0] + r[1]) + (r[2] + r[3])) + ((r[4] + r[5]) + (r[6] + r[7]));
}

__global__ __launch_bounds__(256) void np_blocksums(
    const float* __restrict__ w, float* __restrict__ bs) {
  int b = blockIdx.x * 256 + threadIdx.x;   // [0, 131072)
  const float* a = w + (long)b * 344;
  float s0 = np_leaf_abs(a, 80);
  float s1 = np_leaf_abs(a + 80, 88);
  float s2 = np_leaf_abs(a + 168, 88);
  float s3 = np_leaf_abs(a + 256, 88);
  bs[b] = (s0 + s1) + (s2 + s3);
}

__global__ __launch_bounds__(256) void np_tree_partial(
    const float* __restrict__ bs, float* __restrict__ part) {
  __shared__ float sh[256];
  int t = threadIdx.x;
  const float* a = bs + (long)blockIdx.x * 512;
  sh[t] = a[2 * t] + a[2 * t + 1];
  __syncthreads();
  for (int n = 128; n >= 1; n >>= 1) {
    float x = 0.f;
    if (t < n) x = sh[2 * t] + sh[2 * t + 1];
    __syncthreads();
    if (t < n) sh[t] = x;
    __syncthreads();
  }
  if (t == 0) part[blockIdx.x] = sh[0];
}

__global__ __launch_bounds__(128) void np_tree_final(
    const float* __restrict__ part, float* __restrict__ out) {
  __shared__ float sh[128];
  int t = threadIdx.x;
  sh[t] = part[2 * t] + part[2 * t + 1];
  __syncthreads();
  for (int n = 64; n >= 1; n >>= 1) {
    float x = 0.f;
    if (t < n) x = sh[2 * t] + sh[2 * t + 1];
    __syncthreads();
    if (t < n) sh[t] = x;
    __syncthreads();
  }
  if (t == 0) out[0] = sh[0] / 45088768.0f;
}

// ------------------------------------------------------- weight ternarize
__global__ __launch_bounds__(256) void quant_w(
    const float* __restrict__ w, const float* __restrict__ mean_ptr,
    char* __restrict__ q, long n4) {
  float scale = 1.0f / fmaxf(*mean_ptr, 1e-5f);
  long i = (long)blockIdx.x * blockDim.x + threadIdx.x;
  long stride = (long)gridDim.x * blockDim.x;
  const float4* w4 = (const float4*)w;
  char4* q4 = (char4*)q;
  for (; i < n4; i += stride) {
    float4 v = w4[i];
    char4 c;
    c.x = (char)(int)fminf(1.f, fmaxf(-1.f, rintf(v.x * scale)));
    c.y = (char)(int)fminf(1.f, fmaxf(-1.f, rintf(v.y * scale)));
    c.z = (char)(int)fminf(1.f, fmaxf(-1.f, rintf(v.z * scale)));
    c.w = (char)(int)fminf(1.f, fmaxf(-1.f, rintf(v.w * scale)));
    q4[i] = c;
  }
}

// w_down ternarize with boundary-midpoint hedging (see round 3/4 notes).
#define CORR_MAX 1024
#define WIN 1e-6f

__global__ __launch_bounds__(256) void quant_w_down(
    const float* __restrict__ w, const float* __restrict__ mean_ptr,
    char* __restrict__ q, int* __restrict__ cnt,
    int* __restrict__ ck, float* __restrict__ cv) {
  float scale = 1.0f / fmaxf(*mean_ptr, 1e-5f);
  long i0 = ((long)blockIdx.x * blockDim.x + threadIdx.x) * 4;
  long stride = (long)gridDim.x * blockDim.x * 4;
  for (long i = i0; i < 4096L * 11008L; i += stride) {
    char4 c;
    #pragma unroll
    for (int j = 0; j < 4; j++) {
      float t = w[i + j] * scale;
      float qv = fminf(1.f, fmaxf(-1.f, rintf(t)));
      if (fabsf(fabsf(t) - 0.5f) < WIN) {
        qv = 0.f;
        int idx = atomicAdd(cnt, 1);
        if (idx < CORR_MAX) {
          ck[idx] = (int)(i + j);                 // flat n*11008+k
          cv[idx] = t > 0.f ? 0.5f : -0.5f;
        }
      }
      ((char*)&c)[j] = (char)(int)qv;
    }
    *(char4*)(q + i) = c;
  }
}

__global__ void zero_cnt(int* cnt) { *cnt = 0; }

__global__ __launch_bounds__(64) void apply_corr(
    const int* __restrict__ cnt, const int* __restrict__ ck,
    const float* __restrict__ cv, const char* __restrict__ qh,
    const float* __restrict__ fh, const float* __restrict__ meanw,
    float* __restrict__ out) {
  int r = blockIdx.x * 64 + threadIdx.x;  // 8192 rows
  float fwd = fmaxf(meanw[2], 1e-5f);
  int n = *cnt; if (n > CORR_MAX) n = CORR_MAX;
  float fr = fh[r] * fwd;
  for (int i = 0; i < n; i++) {
    int flat = ck[i];
    int nn = flat / 11008, kk = flat % 11008;
    float qv = (float)qh[(long)r * 11008 + kk];
    out[(long)r * 4096 + nn] += cv[i] * qv * fr;
  }
}

// ---------------------------------------------------------------- reductions
__device__ inline void block_reduce_sum_max_d(double& s, float& m) {
  #pragma unroll
  for (int off = 1; off < 64; off <<= 1) {
    s += __shfl_xor(s, off, 64);
    m = fmaxf(m, __shfl_xor(m, off, 64));
  }
  __shared__ double ssh[4];
  __shared__ float msh[4];
  int wv = threadIdx.x >> 6;
  if ((threadIdx.x & 63) == 0) { ssh[wv] = s; msh[wv] = m; }
  __syncthreads();
  s = (ssh[0] + ssh[1]) + (ssh[2] + ssh[3]);
  m = fmaxf(fmaxf(msh[0], msh[1]), fmaxf(msh[2], msh[3]));
}

// ------------------------------------------------------- activation quant
__device__ inline char quant1d(float x, double rn, double s) {
  double t = (double)x * rn;
  double q = rint(t * s);
  q = fmin(127.0, fmax(-128.0, q));
  return (char)(int)q;
}

__global__ __launch_bounds__(256) void act_quant_x(
    const float* __restrict__ x, char* __restrict__ qx, float* __restrict__ fx) {
  const int row = blockIdx.x;
  const float4* xr = (const float4*)(x + (long)row * 4096);
  float4 v[4];
  double ss = 0.0;
  float am = 0.f;
  #pragma unroll
  for (int i = 0; i < 4; i++) {
    v[i] = xr[i * 256 + threadIdx.x];
    ss += ((double)v[i].x * v[i].x + (double)v[i].y * v[i].y) +
          ((double)v[i].z * v[i].z + (double)v[i].w * v[i].w);
    am = fmaxf(am, fmaxf(fmaxf(fabsf(v[i].x), fabsf(v[i].y)),
                         fmaxf(fabsf(v[i].z), fabsf(v[i].w))));
  }
  block_reduce_sum_max_d(ss, am);
  double rn = 1.0 / sqrt(ss / 4096.0 + EPS);
  double den = fmax((double)am * rn, EPS);
  double s = 127.0 / den;
  if (threadIdx.x == 0) fx[row] = (float)(den / 127.0);
  char4* qr = (char4*)(qx + (long)row * 4096);
  #pragma unroll
  for (int i = 0; i < 4; i++) {
    char4 c;
    c.x = quant1d(v[i].x, rn, s);
    c.y = quant1d(v[i].y, rn, s);
    c.z = quant1d(v[i].z, rn, s);
    c.w = quant1d(v[i].w, rn, s);
    qr[i * 256 + threadIdx.x] = c;
  }
}

__global__ __launch_bounds__(256) void act_quant_h(
    const float* __restrict__ h, char* __restrict__ qh, float* __restrict__ fh) {
  const long row = blockIdx.x;
  const float4* hr = (const float4*)(h + row * 11008);
  double ss = 0.0;
  float am = 0.f;
  for (int i = threadIdx.x; i < 2752; i += 256) {
    float4 v = hr[i];
    ss += ((double)v.x * v.x + (double)v.y * v.y) +
          ((double)v.z * v.z + (double)v.w * v.w);
    am = fmaxf(am, fmaxf(fmaxf(fabsf(v.x), fabsf(v.y)),
                         fmaxf(fabsf(v.z), fabsf(v.w))));
  }
  block_reduce_sum_max_d(ss, am);
  double rn = 1.0 / sqrt(ss / 11008.0 + EPS);
  double den = fmax((double)am * rn, EPS);
  double s = 127.0 / den;
  if (threadIdx.x == 0) fh[row] = (float)(den / 127.0);
  char4* qr = (char4*)(qh + row * 11008);
  for (int i = threadIdx.x; i < 2752; i += 256) {
    float4 v = hr[i];
    char4 c;
    c.x = quant1d(v.x, rn, s);
    c.y = quant1d(v.y, rn, s);
    c.z = quant1d(v.z, rn, s);
    c.w = quant1d(v.w, rn, s);
    qr[i] = c;
  }
}

// =============================================================================
// GEMMs, m218-ordered K-loop: per step {ds_read frags -> issue stage ks+2 ->
// setprio(1) MFMA setprio(0) -> s_waitcnt vmcnt(N!=0) -> s_barrier}. Depth-2
// prefetch over 3 LDS buffers; counted vmcnt never drains in steady state.
// ds_reads FIRST (before the gload issue) so the backend never orders
// LDS-writes against subsequent reads with a drain. Rotation swizzle
// (conflict-free, 0 in PMC since r5) via pre-rotated global source column.
// Tiles sized for multi-block occupancy:
//   gateup: 128x128, 4 waves, 3x24KB=72KB LDS -> 2 blocks/CU, 6 gloads/stage.
//   down:   128x128, 4 waves, 3x16KB=48KB LDS -> 3 blocks/CU, 4 gloads/stage.
// XCD-bijective swizzle, m-fastest within each XCD chunk (B panels L2-hot).
// =============================================================================

__global__ __launch_bounds__(256, 2) void gemm_gateup(
    const char* __restrict__ qx, const char* __restrict__ qwg, const char* __restrict__ qwu,
    const float* __restrict__ meanw, const float* __restrict__ fx, float* __restrict__ h) {
  __shared__ __align__(16) char As[3][8192];
  __shared__ __align__(16) char Bgs[3][8192];
  __shared__ __align__(16) char Bus[3][8192];
  const int t = threadIdx.x;
  const int lane = t & 63;
  const int wv = t >> 6;                       // 0..3
  const int bid = blockIdx.x;                  // 5504 = 8 * 688
  const int swz = (bid & 7) * 688 + (bid >> 3);
  const int m0 = (swz & 63) * 128;             // m fastest within XCD chunk
  const int n0 = (swz >> 6) * 128;
  const int wm = (wv >> 1) * 64;
  const int wn = (wv & 1) * 64;

  const int rowin = lane >> 2;
  const int gcol = (((lane & 3) - ((lane >> 3) & 3)) & 3) * 16;
  const int slot = ((((lane >> 4) + ((lane >> 1) & 3)) & 3) << 4);
  const int lrow = (lane & 15) * 64;

  const char* gA = qx  + (long)(m0 + wv * 32 + rowin) * 4096 + gcol;
  const char* gG = qwg + (long)(n0 + wv * 32 + rowin) * 4096 + gcol;
  const char* gU = qwu + (long)(n0 + wv * 32 + rowin) * 4096 + gcol;
  const long R16 = 16L * 4096;

  int32x4 accg[4][4] = {};
  int32x4 accu[4][4] = {};

  #define STAGE_GU(pb, k0)                                 \
    do {                                                   \
      gload(gA + (k0),       &As [pb][wv * 2048]);         \
      gload(gA + (k0) + R16, &As [pb][wv * 2048 + 1024]);  \
      gload(gG + (k0),       &Bgs[pb][wv * 2048]);         \
      gload(gG + (k0) + R16, &Bgs[pb][wv * 2048 + 1024]);  \
      gload(gU + (k0),       &Bus[pb][wv * 2048]);         \
      gload(gU + (k0) + R16, &Bus[pb][wv * 2048 + 1024]);  \
    } while (0)

  STAGE_GU(0, 0);
  STAGE_GU(1, 64);
  asm volatile("s_waitcnt vmcnt(6)" ::: "memory");  // stage 0 landed
  __builtin_amdgcn_s_barrier();

  for (int ks = 0; ks < 64; ++ks) {
    const int pb = ks % 3;
    const char* ab = &As [pb][0] + wm * 64 + lrow + slot;
    const char* gb = &Bgs[pb][0] + wn * 64 + lrow + slot;
    const char* ub = &Bus[pb][0] + wn * 64 + lrow + slot;
    int32x4 a[4], bg[4], bu[4];
    #pragma unroll
    for (int m = 0; m < 4; m++) a[m] = *(const int32x4*)(ab + m * 1024);
    #pragma unroll
    for (int n = 0; n < 4; n++) bg[n] = *(const int32x4*)(gb + n * 1024);
    #pragma unroll
    for (int n = 0; n < 4; n++) bu[n] = *(const int32x4*)(ub + n * 1024);
    if (ks + 2 < 64) STAGE_GU((ks + 2) % 3, (ks + 2) * 64);
    __builtin_amdgcn_s_setprio(1);
    #pragma unroll
    for (int n = 0; n < 4; n++) {
      #pragma unroll
      for (int m = 0; m < 4; m++) {
        accg[m][n] = __builtin_amdgcn_mfma_i32_16x16x64_i8(a[m], bg[n], accg[m][n], 0, 0, 0);
        accu[m][n] = __builtin_amdgcn_mfma_i32_16x16x64_i8(a[m], bu[n], accu[m][n], 0, 0, 0);
      }
    }
    __builtin_amdgcn_s_setprio(0);
    if (ks < 62)      asm volatile("s_waitcnt vmcnt(6)" ::: "memory");
    else if (ks < 63) asm volatile("s_waitcnt vmcnt(0)" ::: "memory");
    if (ks < 63) __builtin_amdgcn_s_barrier();
  }
  #undef STAGE_GU

  float fwg = fmaxf(meanw[0], 1e-5f);
  float fwu = fmaxf(meanw[1], 1e-5f);
  const int rgrp = lane >> 4;
  const int cidx = lane & 15;
  #pragma unroll
  for (int m = 0; m < 4; m++) {
    #pragma unroll
    for (int r = 0; r < 4; r++) {
      int grow = m0 + wm + m * 16 + rgrp * 4 + r;
      float fxr = fx[grow];
      float sg = fxr * fwg, su = fxr * fwu;
      #pragma unroll
      for (int n = 0; n < 4; n++) {
        float g = (float)accg[m][n][r] * sg;
        float u = (float)accu[m][n][r] * su;
        float hv = g / (1.f + expf(-g)) * u;
        h[(long)grow * 11008 + (n0 + wn + n * 16 + cidx)] = hv;
      }
    }
  }
}

__global__ __launch_bounds__(256, 3) void gemm_down(
    const char* __restrict__ qh, const char* __restrict__ qwd,
    const float* __restrict__ mean_wd, const float* __restrict__ fh,
    float* __restrict__ out) {
  __shared__ __align__(16) char As[3][8192];
  __shared__ __align__(16) char Bs[3][8192];
  const int t = threadIdx.x;
  const int lane = t & 63;
  const int wv = t >> 6;
  const int bid = blockIdx.x;                  // 2048 = 8 * 256
  const int swz = (bid & 7) * 256 + (bid >> 3);
  const int m0 = (swz & 63) * 128;
  const int n0 = (swz >> 6) * 128;
  const int wm = (wv >> 1) * 64;
  const int wn = (wv & 1) * 64;

  const int rowin = lane >> 2;
  const int gcol = (((lane & 3) - ((lane >> 3) & 3)) & 3) * 16;
  const int slot = ((((lane >> 4) + ((lane >> 1) & 3)) & 3) << 4);
  const int lrow = (lane & 15) * 64;

  const char* gA = qh  + (long)(m0 + wv * 32 + rowin) * 11008 + gcol;
  const char* gB = qwd + (long)(n0 + wv * 32 + rowin) * 11008 + gcol;
  const long R16 = 16L * 11008;

  int32x4 acc[4][4] = {};

  #define STAGE_DN(pb, k0)                                \
    do {                                                  \
      gload(gA + (k0),       &As[pb][wv * 2048]);         \
      gload(gA + (k0) + R16, &As[pb][wv * 2048 + 1024]);  \
      gload(gB + (k0),       &Bs[pb][wv * 2048]);         \
      gload(gB + (k0) + R16, &Bs[pb][wv * 2048 + 1024]);  \
    } while (0)

  STAGE_DN(0, 0);
  STAGE_DN(1, 64);
  asm volatile("s_waitcnt vmcnt(4)" ::: "memory");
  __builtin_amdgcn_s_barrier();

  for (int ks = 0; ks < 172; ++ks) {
    const int pb = ks % 3;
    const char* ab = &As[pb][0] + wm * 64 + lrow + slot;
    const char* bb = &Bs[pb][0] + wn * 64 + lrow + slot;
    int32x4 a[4], b[4];
    #pragma unroll
    for (int m = 0; m < 4; m++) a[m] = *(const int32x4*)(ab + m * 1024);
    #pragma unroll
    for (int n = 0; n < 4; n++) b[n] = *(const int32x4*)(bb + n * 1024);
    if (ks + 2 < 172) STAGE_DN((ks + 2) % 3, (ks + 2) * 64);
    __builtin_amdgcn_s_setprio(1);
    #pragma unroll
    for (int n = 0; n < 4; n++) {
      #pragma unroll
      for (int m = 0; m < 4; m++)
        acc[m][n] = __builtin_amdgcn_mfma_i32_16x16x64_i8(a[m], b[n], acc[m][n], 0, 0, 0);
    }
    __builtin_amdgcn_s_setprio(0);
    if (ks < 170)      asm volatile("s_waitcnt vmcnt(4)" ::: "memory");
    else if (ks < 171) asm volatile("s_waitcnt vmcnt(0)" ::: "memory");
    if (ks < 171) __builtin_amdgcn_s_barrier();
  }
  #undef STAGE_DN

  float fwd = fmaxf(mean_wd[0], 1e-5f);
  const int rgrp = lane >> 4;
  const int cidx = lane & 15;
  #pragma unroll
  for (int m = 0; m < 4; m++) {
    #pragma unroll
    for (int r = 0; r < 4; r++) {
      int grow = m0 + wm + m * 16 + rgrp * 4 + r;
      float f = fh[grow] * fwd;
      #pragma unroll
      for (int n = 0; n < 4; n++) {
        out[(long)grow * 4096 + (n0 + wn + n * 16 + cidx)] =
            (float)acc[m][n][r] * f;
      }
    }
  }
}

// ---------------------------------------------------------------- launch
extern "C" void kernel_launch(void* const* d_in, const int* in_sizes, int n_in,
                              void* d_out, int out_size, void* d_ws, size_t ws_size,
                              hipStream_t stream) {
  const float* x      = (const float*)d_in[0];
  const float* w_gate = (const float*)d_in[1];
  const float* w_up   = (const float*)d_in[2];
  const float* w_down = (const float*)d_in[3];
  float* out = (float*)d_out;

  const long NW = 11008L * 4096L;     // 45088768 per weight
  const long NX = 8192L * 4096L;      // 33554432
  const long NH = 8192L * 11008L;     // 90177536

  char* ws  = (char*)d_ws;
  char* qwg = ws;
  char* qwu = qwg + NW;
  char* qwd = qwu + NW;
  char* qx  = qwd + NW;
  char* qh  = qx + NX;
  float* h  = (float*)(qh + NH);
  float* fx = h + NH;                 // 8192 floats
  float* fh = fx + 8192;              // 8192 floats
  float* meanw = fh + 8192;           // [0]=gate [1]=up [2]=down (+pad)
  float* bs    = meanw + 4;           // 131072 floats (reused per matrix)
  float* tmp   = bs + 131072;         // 256 floats used
  int*   ccnt  = (int*)(tmp + 65536);
  int*   ck    = ccnt + 4;            // CORR_MAX ints
  float* cv    = (float*)(ck + CORR_MAX);

  zero_cnt<<<1, 1, 0, stream>>>(ccnt);

  // numpy-style fp32 pairwise means (pairing bit-identical to sequential tree)
  np_blocksums<<<512, 256, 0, stream>>>(w_gate, bs);
  np_tree_partial<<<256, 256, 0, stream>>>(bs, tmp);
  np_tree_final<<<1, 128, 0, stream>>>(tmp, meanw + 0);
  np_blocksums<<<512, 256, 0, stream>>>(w_up, bs);
  np_tree_partial<<<256, 256, 0, stream>>>(bs, tmp);
  np_tree_final<<<1, 128, 0, stream>>>(tmp, meanw + 1);
  np_blocksums<<<512, 256, 0, stream>>>(w_down, bs);
  np_tree_partial<<<256, 256, 0, stream>>>(bs, tmp);
  np_tree_final<<<1, 128, 0, stream>>>(tmp, meanw + 2);

  quant_w<<<4096, 256, 0, stream>>>(w_gate, meanw + 0, qwg, NW / 4);
  quant_w<<<4096, 256, 0, stream>>>(w_up,   meanw + 1, qwu, NW / 4);
  quant_w_down<<<4096, 256, 0, stream>>>(w_down, meanw + 2, qwd, ccnt, ck, cv);

  act_quant_x<<<8192, 256, 0, stream>>>(x, qx, fx);

  gemm_gateup<<<5504, 256, 0, stream>>>(qx, qwg, qwu, meanw, fx, h);

  act_quant_h<<<8192, 256, 0, stream>>>(h, qh, fh);

  gemm_down<<<2048, 256, 0, stream>>>(qh, qwd, meanw + 2, fh, out);

  apply_corr<<<128, 64, 0, stream>>>(ccnt, ck, cv, qh, fh, meanw, out);
}

// Round 10
// 1735.890 us; speedup vs baseline: 1.3106x; 1.0836x over previous
//
#include <hip/hip_runtime.h>
#include <hip/hip_bf16.h>
#include <cstdint>

#define EPS 1e-5

typedef __attribute__((ext_vector_type(4))) int int32x4;
typedef __attribute__((ext_vector_type(16))) int int32x16;

// ---------------------------------------------------------------- async global->LDS
__device__ __forceinline__ void gload(const char* g, char* l) {
  __builtin_amdgcn_global_load_lds(
      (const __attribute__((address_space(1))) unsigned int*)g,
      (__attribute__((address_space(3))) unsigned int*)l, 16, 0, 0);
}

// =============================================================================
// numpy-exact fp32 pairwise mean of |w| (see round 2-4 notes).
// =============================================================================
__device__ inline float np_leaf_abs(const float* __restrict__ a, int n) {
  float r[8];
  #pragma unroll
  for (int j = 0; j < 8; j++) r[j] = fabsf(a[j]);
  for (int i = 8; i < n; i += 8) {
    #pragma unroll
    for (int j = 0; j < 8; j++) r[j] += fabsf(a[i + j]);
  }
  return ((r[0] + r[1]) + (r[2] + r[3])) + ((r[4] + r[5]) + (r[6] + r[7]));
}

__global__ __launch_bounds__(256) void np_blocksums(
    const float* __restrict__ w, float* __restrict__ bs) {
  int b = blockIdx.x * 256 + threadIdx.x;   // [0, 131072)
  const float* a = w + (long)b * 344;
  float s0 = np_leaf_abs(a, 80);
  float s1 = np_leaf_abs(a + 80, 88);
  float s2 = np_leaf_abs(a + 168, 88);
  float s3 = np_leaf_abs(a + 256, 88);
  bs[b] = (s0 + s1) + (s2 + s3);
}

__global__ __launch_bounds__(256) void np_tree_partial(
    const float* __restrict__ bs, float* __restrict__ part) {
  __shared__ float sh[256];
  int t = threadIdx.x;
  const float* a = bs + (long)blockIdx.x * 512;
  sh[t] = a[2 * t] + a[2 * t + 1];
  __syncthreads();
  for (int n = 128; n >= 1; n >>= 1) {
    float x = 0.f;
    if (t < n) x = sh[2 * t] + sh[2 * t + 1];
    __syncthreads();
    if (t < n) sh[t] = x;
    __syncthreads();
  }
  if (t == 0) part[blockIdx.x] = sh[0];
}

__global__ __launch_bounds__(128) void np_tree_final(
    const float* __restrict__ part, float* __restrict__ out) {
  __shared__ float sh[128];
  int t = threadIdx.x;
  sh[t] = part[2 * t] + part[2 * t + 1];
  __syncthreads();
  for (int n = 64; n >= 1; n >>= 1) {
    float x = 0.f;
    if (t < n) x = sh[2 * t] + sh[2 * t + 1];
    __syncthreads();
    if (t < n) sh[t] = x;
    __syncthreads();
  }
  if (t == 0) out[0] = sh[0] / 45088768.0f;
}

// ------------------------------------------------------- weight ternarize
__global__ __launch_bounds__(256) void quant_w(
    const float* __restrict__ w, const float* __restrict__ mean_ptr,
    char* __restrict__ q, long n4) {
  float scale = 1.0f / fmaxf(*mean_ptr, 1e-5f);
  long i = (long)blockIdx.x * blockDim.x + threadIdx.x;
  long stride = (long)gridDim.x * blockDim.x;
  const float4* w4 = (const float4*)w;
  char4* q4 = (char4*)q;
  for (; i < n4; i += stride) {
    float4 v = w4[i];
    char4 c;
    c.x = (char)(int)fminf(1.f, fmaxf(-1.f, rintf(v.x * scale)));
    c.y = (char)(int)fminf(1.f, fmaxf(-1.f, rintf(v.y * scale)));
    c.z = (char)(int)fminf(1.f, fmaxf(-1.f, rintf(v.z * scale)));
    c.w = (char)(int)fminf(1.f, fmaxf(-1.f, rintf(v.w * scale)));
    q4[i] = c;
  }
}

// w_down ternarize with boundary-midpoint hedging (see round 3/4 notes).
#define CORR_MAX 1024
#define WIN 1e-6f

__global__ __launch_bounds__(256) void quant_w_down(
    const float* __restrict__ w, const float* __restrict__ mean_ptr,
    char* __restrict__ q, int* __restrict__ cnt,
    int* __restrict__ ck, float* __restrict__ cv) {
  float scale = 1.0f / fmaxf(*mean_ptr, 1e-5f);
  long i0 = ((long)blockIdx.x * blockDim.x + threadIdx.x) * 4;
  long stride = (long)gridDim.x * blockDim.x * 4;
  for (long i = i0; i < 4096L * 11008L; i += stride) {
    char4 c;
    #pragma unroll
    for (int j = 0; j < 4; j++) {
      float t = w[i + j] * scale;
      float qv = fminf(1.f, fmaxf(-1.f, rintf(t)));
      if (fabsf(fabsf(t) - 0.5f) < WIN) {
        qv = 0.f;
        int idx = atomicAdd(cnt, 1);
        if (idx < CORR_MAX) {
          ck[idx] = (int)(i + j);                 // flat n*11008+k
          cv[idx] = t > 0.f ? 0.5f : -0.5f;
        }
      }
      ((char*)&c)[j] = (char)(int)qv;
    }
    *(char4*)(q + i) = c;
  }
}

__global__ void zero_cnt(int* cnt) { *cnt = 0; }

__global__ __launch_bounds__(64) void apply_corr(
    const int* __restrict__ cnt, const int* __restrict__ ck,
    const float* __restrict__ cv, const char* __restrict__ qh,
    const float* __restrict__ fh, const float* __restrict__ meanw,
    float* __restrict__ out) {
  int r = blockIdx.x * 64 + threadIdx.x;  // 8192 rows
  float fwd = fmaxf(meanw[2], 1e-5f);
  int n = *cnt; if (n > CORR_MAX) n = CORR_MAX;
  float fr = fh[r] * fwd;
  for (int i = 0; i < n; i++) {
    int flat = ck[i];
    int nn = flat / 11008, kk = flat % 11008;
    float qv = (float)qh[(long)r * 11008 + kk];
    out[(long)r * 4096 + nn] += cv[i] * qv * fr;
  }
}

// ---------------------------------------------------------------- reductions
__device__ inline void block_reduce_sum_max_d(double& s, float& m) {
  #pragma unroll
  for (int off = 1; off < 64; off <<= 1) {
    s += __shfl_xor(s, off, 64);
    m = fmaxf(m, __shfl_xor(m, off, 64));
  }
  __shared__ double ssh[4];
  __shared__ float msh[4];
  int wv = threadIdx.x >> 6;
  if ((threadIdx.x & 63) == 0) { ssh[wv] = s; msh[wv] = m; }
  __syncthreads();
  s = (ssh[0] + ssh[1]) + (ssh[2] + ssh[3]);
  m = fmaxf(fmaxf(msh[0], msh[1]), fmaxf(msh[2], msh[3]));
}

// ------------------------------------------------------- activation quant
__device__ inline char quant1d(float x, double rn, double s) {
  double t = (double)x * rn;
  double q = rint(t * s);
  q = fmin(127.0, fmax(-128.0, q));
  return (char)(int)q;
}

__global__ __launch_bounds__(256) void act_quant_x(
    const float* __restrict__ x, char* __restrict__ qx, float* __restrict__ fx) {
  const int row = blockIdx.x;
  const float4* xr = (const float4*)(x + (long)row * 4096);
  float4 v[4];
  double ss = 0.0;
  float am = 0.f;
  #pragma unroll
  for (int i = 0; i < 4; i++) {
    v[i] = xr[i * 256 + threadIdx.x];
    ss += ((double)v[i].x * v[i].x + (double)v[i].y * v[i].y) +
          ((double)v[i].z * v[i].z + (double)v[i].w * v[i].w);
    am = fmaxf(am, fmaxf(fmaxf(fabsf(v[i].x), fabsf(v[i].y)),
                         fmaxf(fabsf(v[i].z), fabsf(v[i].w))));
  }
  block_reduce_sum_max_d(ss, am);
  double rn = 1.0 / sqrt(ss / 4096.0 + EPS);
  double den = fmax((double)am * rn, EPS);
  double s = 127.0 / den;
  if (threadIdx.x == 0) fx[row] = (float)(den / 127.0);
  char4* qr = (char4*)(qx + (long)row * 4096);
  #pragma unroll
  for (int i = 0; i < 4; i++) {
    char4 c;
    c.x = quant1d(v[i].x, rn, s);
    c.y = quant1d(v[i].y, rn, s);
    c.z = quant1d(v[i].z, rn, s);
    c.w = quant1d(v[i].w, rn, s);
    qr[i * 256 + threadIdx.x] = c;
  }
}

// h row cached in LDS (44KB) so the quant pass doesn't re-read 360MB from HBM.
__global__ __launch_bounds__(256) void act_quant_h(
    const float* __restrict__ h, char* __restrict__ qh, float* __restrict__ fh) {
  __shared__ float4 hrow4[2752];
  const long row = blockIdx.x;
  const float4* hr = (const float4*)(h + row * 11008);
  double ss = 0.0;
  float am = 0.f;
  for (int i = threadIdx.x; i < 2752; i += 256) {
    float4 v = hr[i];
    hrow4[i] = v;
    ss += ((double)v.x * v.x + (double)v.y * v.y) +
          ((double)v.z * v.z + (double)v.w * v.w);
    am = fmaxf(am, fmaxf(fmaxf(fabsf(v.x), fabsf(v.y)),
                         fmaxf(fabsf(v.z), fabsf(v.w))));
  }
  block_reduce_sum_max_d(ss, am);   // contains __syncthreads (covers hrow4)
  double rn = 1.0 / sqrt(ss / 11008.0 + EPS);
  double den = fmax((double)am * rn, EPS);
  double s = 127.0 / den;
  if (threadIdx.x == 0) fh[row] = (float)(den / 127.0);
  char4* qr = (char4*)(qh + row * 11008);
  for (int i = threadIdx.x; i < 2752; i += 256) {
    float4 v = hrow4[i];
    char4 c;
    c.x = quant1d(v.x, rn, s);
    c.y = quant1d(v.y, rn, s);
    c.z = quant1d(v.z, rn, s);
    c.w = quant1d(v.w, rn, s);
    qr[i] = c;
  }
}

// =============================================================================
// GEMMs: mfma_i32_32x32x32_i8 (4404 TOPS ceiling, half the instruction count of
// 16x16x64 for the same tile => bigger scheduler windows for cross-wave
// LDS/MFMA overlap). m218-ordered K-loop, depth-2 prefetch over 3 LDS buffers
// selected by POINTER ROTATION (no %3 VALU). Counted vmcnt(6); raw s_barrier.
// Rotation swizzle as r5-r9 (PMC-verified conflict-free): LDS[row][slot] holds
// global k-slot (slot - (row>>1))&3; reader uses slot=(kslot+(row>>1))&3.
// 32-row b128 reads: lanes 0-7 hit all 32 banks (conflict-free by design).
//   gateup: 128x128 tile, 4 waves (2x2 of 64x64), 72KB LDS -> 2 blocks/CU.
//   down:   128x256 tile, 4 waves (2m x 2n of 64x128), 72KB LDS -> 2 blocks/CU.
// XCD-bijective swizzle, m-fastest: co-resident full m-sweep shares B in L2.
// =============================================================================

__global__ __launch_bounds__(256, 2) void gemm_gateup(
    const char* __restrict__ qx, const char* __restrict__ qwg, const char* __restrict__ qwu,
    const float* __restrict__ meanw, const float* __restrict__ fx, float* __restrict__ h) {
  __shared__ __align__(16) char As[3][8192];
  __shared__ __align__(16) char Bgs[3][8192];
  __shared__ __align__(16) char Bus[3][8192];
  const int t = threadIdx.x;
  const int lane = t & 63;
  const int wv = t >> 6;                       // 0..3
  const int bid = blockIdx.x;                  // 5504 = 8 * 688
  const int swz = (bid & 7) * 688 + (bid >> 3);
  const int m0 = (swz & 63) * 128;             // m fastest within XCD chunk
  const int n0 = (swz >> 6) * 128;
  const int wm = (wv >> 1) * 64;
  const int wn = (wv & 1) * 64;

  // staging addressing (identical to r9)
  const int rowin = lane >> 2;
  const int gcol = (((lane & 3) - ((lane >> 3) & 3)) & 3) * 16;
  // reader addressing for 32x32x32 frags
  const int r31 = lane & 31;
  const int rb64 = r31 * 64;
  const int l5 = lane >> 5;
  const int rot0 = (((l5 + (r31 >> 1)) & 3)) << 4;       // k-half 0
  const int rot1 = (((2 + l5 + (r31 >> 1)) & 3)) << 4;   // k-half 1

  const char* gA = qx  + (long)(m0 + wv * 32 + rowin) * 4096 + gcol;
  const char* gG = qwg + (long)(n0 + wv * 32 + rowin) * 4096 + gcol;
  const char* gU = qwu + (long)(n0 + wv * 32 + rowin) * 4096 + gcol;
  const long R16 = 16L * 4096;

  int32x16 accg[2][2] = {};
  int32x16 accu[2][2] = {};

  char* A0 = &As[0][0];  char* A1 = &As[1][0];  char* A2 = &As[2][0];
  char* G0 = &Bgs[0][0]; char* G1 = &Bgs[1][0]; char* G2 = &Bgs[2][0];
  char* U0 = &Bus[0][0]; char* U1 = &Bus[1][0]; char* U2 = &Bus[2][0];

  #define STAGE_GU(pa, pg, pu, k0)                 \
    do {                                           \
      gload(gA + (k0),       pa + wv * 2048);      \
      gload(gA + (k0) + R16, pa + wv * 2048 + 1024); \
      gload(gG + (k0),       pg + wv * 2048);      \
      gload(gG + (k0) + R16, pg + wv * 2048 + 1024); \
      gload(gU + (k0),       pu + wv * 2048);      \
      gload(gU + (k0) + R16, pu + wv * 2048 + 1024); \
    } while (0)

  STAGE_GU(A0, G0, U0, 0);
  STAGE_GU(A1, G1, U1, 64);
  asm volatile("s_waitcnt vmcnt(6)" ::: "memory");  // stage 0 landed
  __builtin_amdgcn_s_barrier();

  for (int ks = 0; ks < 64; ++ks) {
    // ds_read fragments from current buffer (A0/G0/U0)
    int32x4 a[2][2], bg[2][2], bu[2][2];
    #pragma unroll
    for (int mi = 0; mi < 2; mi++) {
      a[mi][0] = *(const int32x4*)(A0 + (wm + mi * 32) * 64 + rb64 + rot0);
      a[mi][1] = *(const int32x4*)(A0 + (wm + mi * 32) * 64 + rb64 + rot1);
    }
    #pragma unroll
    for (int ni = 0; ni < 2; ni++) {
      bg[ni][0] = *(const int32x4*)(G0 + (wn + ni * 32) * 64 + rb64 + rot0);
      bg[ni][1] = *(const int32x4*)(G0 + (wn + ni * 32) * 64 + rb64 + rot1);
      bu[ni][0] = *(const int32x4*)(U0 + (wn + ni * 32) * 64 + rb64 + rot0);
      bu[ni][1] = *(const int32x4*)(U0 + (wn + ni * 32) * 64 + rb64 + rot1);
    }
    if (ks + 2 < 64) STAGE_GU(A2, G2, U2, (ks + 2) * 64);
    __builtin_amdgcn_s_setprio(1);
    #pragma unroll
    for (int kh = 0; kh < 2; kh++) {
      #pragma unroll
      for (int ni = 0; ni < 2; ni++) {
        #pragma unroll
        for (int mi = 0; mi < 2; mi++) {
          accg[mi][ni] = __builtin_amdgcn_mfma_i32_32x32x32_i8(
              a[mi][kh], bg[ni][kh], accg[mi][ni], 0, 0, 0);
          accu[mi][ni] = __builtin_amdgcn_mfma_i32_32x32x32_i8(
              a[mi][kh], bu[ni][kh], accu[mi][ni], 0, 0, 0);
        }
      }
    }
    __builtin_amdgcn_s_setprio(0);
    if (ks < 62)      asm volatile("s_waitcnt vmcnt(6)" ::: "memory");
    else if (ks < 63) asm volatile("s_waitcnt vmcnt(0)" ::: "memory");
    if (ks < 63) __builtin_amdgcn_s_barrier();
    // rotate buffers: cur<-nxt, nxt<-stg, stg<-old cur
    char* tA = A0; A0 = A1; A1 = A2; A2 = tA;
    char* tG = G0; G0 = G1; G1 = G2; G2 = tG;
    char* tU = U0; U0 = U1; U1 = U2; U2 = tU;
  }
  #undef STAGE_GU

  float fwg = fmaxf(meanw[0], 1e-5f);
  float fwu = fmaxf(meanw[1], 1e-5f);
  const int col = lane & 31;
  const int rbase = (lane >> 5) * 4;
  #pragma unroll
  for (int mi = 0; mi < 2; mi++) {
    #pragma unroll
    for (int reg = 0; reg < 16; reg++) {
      int grow = m0 + wm + mi * 32 + rbase + (reg & 3) + 8 * (reg >> 2);
      float fxr = fx[grow];
      float sg = fxr * fwg, su = fxr * fwu;
      #pragma unroll
      for (int ni = 0; ni < 2; ni++) {
        float g = (float)accg[mi][ni][reg] * sg;
        float u = (float)accu[mi][ni][reg] * su;
        float hv = g / (1.f + expf(-g)) * u;
        h[(long)grow * 11008 + (n0 + wn + ni * 32 + col)] = hv;
      }
    }
  }
}

__global__ __launch_bounds__(256, 2) void gemm_down(
    const char* __restrict__ qh, const char* __restrict__ qwd,
    const float* __restrict__ mean_wd, const float* __restrict__ fh,
    float* __restrict__ out) {
  __shared__ __align__(16) char As[3][8192];
  __shared__ __align__(16) char Bs[3][16384];
  const int t = threadIdx.x;
  const int lane = t & 63;
  const int wv = t >> 6;
  const int bid = blockIdx.x;                  // 1024 = 8 * 128
  const int swz = (bid & 7) * 128 + (bid >> 3);
  const int m0 = (swz & 63) * 128;             // 64 m-blocks
  const int n0 = (swz >> 6) * 256;             // 16 n-blocks
  const int wm = (wv >> 1) * 64;
  const int wn = (wv & 1) * 128;

  const int rowin = lane >> 2;
  const int gcol = (((lane & 3) - ((lane >> 3) & 3)) & 3) * 16;
  const int r31 = lane & 31;
  const int rb64 = r31 * 64;
  const int l5 = lane >> 5;
  const int rot0 = (((l5 + (r31 >> 1)) & 3)) << 4;
  const int rot1 = (((2 + l5 + (r31 >> 1)) & 3)) << 4;

  const char* gA = qh  + (long)(m0 + wv * 32 + rowin) * 11008 + gcol;
  const char* gB = qwd + (long)(n0 + wv * 64 + rowin) * 11008 + gcol;
  const long R16 = 16L * 11008;

  int32x16 acc[2][4] = {};

  char* A0 = &As[0][0]; char* A1 = &As[1][0]; char* A2 = &As[2][0];
  char* B0 = &Bs[0][0]; char* B1 = &Bs[1][0]; char* B2 = &Bs[2][0];

  #define STAGE_DN(pa, pb, k0)                          \
    do {                                                \
      gload(gA + (k0),           pa + wv * 2048);       \
      gload(gA + (k0) + R16,     pa + wv * 2048 + 1024);\
      gload(gB + (k0),           pb + wv * 4096);       \
      gload(gB + (k0) + R16,     pb + wv * 4096 + 1024);\
      gload(gB + (k0) + 2 * R16, pb + wv * 4096 + 2048);\
      gload(gB + (k0) + 3 * R16, pb + wv * 4096 + 3072);\
    } while (0)

  STAGE_DN(A0, B0, 0);
  STAGE_DN(A1, B1, 64);
  asm volatile("s_waitcnt vmcnt(6)" ::: "memory");
  __builtin_amdgcn_s_barrier();

  for (int ks = 0; ks < 172; ++ks) {
    int32x4 a[2][2], b[4][2];
    #pragma unroll
    for (int mi = 0; mi < 2; mi++) {
      a[mi][0] = *(const int32x4*)(A0 + (wm + mi * 32) * 64 + rb64 + rot0);
      a[mi][1] = *(const int32x4*)(A0 + (wm + mi * 32) * 64 + rb64 + rot1);
    }
    #pragma unroll
    for (int ni = 0; ni < 4; ni++) {
      b[ni][0] = *(const int32x4*)(B0 + (wn + ni * 32) * 64 + rb64 + rot0);
      b[ni][1] = *(const int32x4*)(B0 + (wn + ni * 32) * 64 + rb64 + rot1);
    }
    if (ks + 2 < 172) STAGE_DN(A2, B2, (ks + 2) * 64);
    __builtin_amdgcn_s_setprio(1);
    #pragma unroll
    for (int kh = 0; kh < 2; kh++) {
      #pragma unroll
      for (int ni = 0; ni < 4; ni++) {
        #pragma unroll
        for (int mi = 0; mi < 2; mi++) {
          acc[mi][ni] = __builtin_amdgcn_mfma_i32_32x32x32_i8(
              a[mi][kh], b[ni][kh], acc[mi][ni], 0, 0, 0);
        }
      }
    }
    __builtin_amdgcn_s_setprio(0);
    if (ks < 170)      asm volatile("s_waitcnt vmcnt(6)" ::: "memory");
    else if (ks < 171) asm volatile("s_waitcnt vmcnt(0)" ::: "memory");
    if (ks < 171) __builtin_amdgcn_s_barrier();
    char* tA = A0; A0 = A1; A1 = A2; A2 = tA;
    char* tB = B0; B0 = B1; B1 = B2; B2 = tB;
  }
  #undef STAGE_DN

  float fwd = fmaxf(mean_wd[0], 1e-5f);
  const int col = lane & 31;
  const int rbase = (lane >> 5) * 4;
  #pragma unroll
  for (int mi = 0; mi < 2; mi++) {
    #pragma unroll
    for (int reg = 0; reg < 16; reg++) {
      int grow = m0 + wm + mi * 32 + rbase + (reg & 3) + 8 * (reg >> 2);
      float f = fh[grow] * fwd;
      #pragma unroll
      for (int ni = 0; ni < 4; ni++) {
        out[(long)grow * 4096 + (n0 + wn + ni * 32 + col)] =
            (float)acc[mi][ni][reg] * f;
      }
    }
  }
}

// ---------------------------------------------------------------- launch
extern "C" void kernel_launch(void* const* d_in, const int* in_sizes, int n_in,
                              void* d_out, int out_size, void* d_ws, size_t ws_size,
                              hipStream_t stream) {
  const float* x      = (const float*)d_in[0];
  const float* w_gate = (const float*)d_in[1];
  const float* w_up   = (const float*)d_in[2];
  const float* w_down = (const float*)d_in[3];
  float* out = (float*)d_out;

  const long NW = 11008L * 4096L;     // 45088768 per weight
  const long NX = 8192L * 4096L;      // 33554432
  const long NH = 8192L * 11008L;     // 90177536

  char* ws  = (char*)d_ws;
  char* qwg = ws;
  char* qwu = qwg + NW;
  char* qwd = qwu + NW;
  char* qx  = qwd + NW;
  char* qh  = qx + NX;
  float* h  = (float*)(qh + NH);
  float* fx = h + NH;                 // 8192 floats
  float* fh = fx + 8192;              // 8192 floats
  float* meanw = fh + 8192;           // [0]=gate [1]=up [2]=down (+pad)
  float* bs    = meanw + 4;           // 131072 floats (reused per matrix)
  float* tmp   = bs + 131072;         // 256 floats used
  int*   ccnt  = (int*)(tmp + 65536);
  int*   ck    = ccnt + 4;            // CORR_MAX ints
  float* cv    = (float*)(ck + CORR_MAX);

  zero_cnt<<<1, 1, 0, stream>>>(ccnt);

  // numpy-style fp32 pairwise means (pairing bit-identical to sequential tree)
  np_blocksums<<<512, 256, 0, stream>>>(w_gate, bs);
  np_tree_partial<<<256, 256, 0, stream>>>(bs, tmp);
  np_tree_final<<<1, 128, 0, stream>>>(tmp, meanw + 0);
  np_blocksums<<<512, 256, 0, stream>>>(w_up, bs);
  np_tree_partial<<<256, 256, 0, stream>>>(bs, tmp);
  np_tree_final<<<1, 128, 0, stream>>>(tmp, meanw + 1);
  np_blocksums<<<512, 256, 0, stream>>>(w_down, bs);
  np_tree_partial<<<256, 256, 0, stream>>>(bs, tmp);
  np_tree_final<<<1, 128, 0, stream>>>(tmp, meanw + 2);

  quant_w<<<4096, 256, 0, stream>>>(w_gate, meanw + 0, qwg, NW / 4);
  quant_w<<<4096, 256, 0, stream>>>(w_up,   meanw + 1, qwu, NW / 4);
  quant_w_down<<<4096, 256, 0, stream>>>(w_down, meanw + 2, qwd, ccnt, ck, cv);

  act_quant_x<<<8192, 256, 0, stream>>>(x, qx, fx);

  gemm_gateup<<<5504, 256, 0, stream>>>(qx, qwg, qwu, meanw, fx, h);

  act_quant_h<<<8192, 256, 0, stream>>>(h, qh, fh);

  gemm_down<<<1024, 256, 0, stream>>>(qh, qwd, meanw + 2, fh, out);

  apply_corr<<<128, 64, 0, stream>>>(ccnt, ck, cv, qh, fh, meanw, out);
}

// Round 11
// 1689.654 us; speedup vs baseline: 1.3465x; 1.0274x over previous
//
#include <hip/hip_runtime.h>
#include <hip/hip_bf16.h>
#include <cstdint>

#define EPS 1e-5

typedef __attribute__((ext_vector_type(4))) int int32x4;

// ---------------------------------------------------------------- async global->LDS
__device__ __forceinline__ void gload(const char* g, char* l) {
  __builtin_amdgcn_global_load_lds(
      (const __attribute__((address_space(1))) unsigned int*)g,
      (__attribute__((address_space(3))) unsigned int*)l, 16, 0, 0);
}

// =============================================================================
// numpy-exact fp32 pairwise mean of |w| (see round 2-4 notes). Fused: all three
// weight matrices in one kernel per tree level.
// =============================================================================
__device__ inline float np_leaf_abs(const float* __restrict__ a, int n) {
  float r[8];
  #pragma unroll
  for (int j = 0; j < 8; j++) r[j] = fabsf(a[j]);
  for (int i = 8; i < n; i += 8) {
    #pragma unroll
    for (int j = 0; j < 8; j++) r[j] += fabsf(a[i + j]);
  }
  return ((r[0] + r[1]) + (r[2] + r[3])) + ((r[4] + r[5]) + (r[6] + r[7]));
}

__global__ __launch_bounds__(256) void np_blocksums3(
    const float* __restrict__ w0, const float* __restrict__ w1,
    const float* __restrict__ w2, float* __restrict__ bs) {
  int b = blockIdx.x * 256 + threadIdx.x;       // [0, 393216)
  const float* w = (b < 131072) ? w0 : (b < 262144 ? w1 : w2);
  long lb = b & 131071;
  const float* a = w + lb * 344;
  float s0 = np_leaf_abs(a, 80);
  float s1 = np_leaf_abs(a + 80, 88);
  float s2 = np_leaf_abs(a + 168, 88);
  float s3 = np_leaf_abs(a + 256, 88);
  bs[b] = (s0 + s1) + (s2 + s3);
}

__global__ __launch_bounds__(256) void np_tree_partial3(
    const float* __restrict__ bs, float* __restrict__ part) {
  __shared__ float sh[256];
  int t = threadIdx.x;
  const float* a = bs + (long)blockIdx.x * 512;   // grid 768 = 3*256
  sh[t] = a[2 * t] + a[2 * t + 1];
  __syncthreads();
  for (int n = 128; n >= 1; n >>= 1) {
    float x = 0.f;
    if (t < n) x = sh[2 * t] + sh[2 * t + 1];
    __syncthreads();
    if (t < n) sh[t] = x;
    __syncthreads();
  }
  if (t == 0) part[blockIdx.x] = sh[0];
}

__global__ __launch_bounds__(128) void np_tree_final3(
    const float* __restrict__ part, float* __restrict__ meanw) {
  __shared__ float sh[128];
  int t = threadIdx.x;
  const float* p = part + blockIdx.x * 256;     // grid 3
  sh[t] = p[2 * t] + p[2 * t + 1];
  __syncthreads();
  for (int n = 64; n >= 1; n >>= 1) {
    float x = 0.f;
    if (t < n) x = sh[2 * t] + sh[2 * t + 1];
    __syncthreads();
    if (t < n) sh[t] = x;
    __syncthreads();
  }
  if (t == 0) meanw[blockIdx.x] = sh[0] / 45088768.0f;
}

// ------------------------------------------------------- weight ternarize
// gate + up fused (grid 8192); w_down separate (midpoint hedging).
__global__ __launch_bounds__(256) void quant_w_gu(
    const float* __restrict__ wg, const float* __restrict__ wu,
    const float* __restrict__ meanw, char* __restrict__ qg, char* __restrict__ qu,
    long n4) {
  int half = (blockIdx.x >= 4096);
  const float* w = half ? wu : wg;
  char* q = half ? qu : qg;
  float scale = 1.0f / fmaxf(meanw[half], 1e-5f);
  long i = (long)(blockIdx.x & 4095) * blockDim.x + threadIdx.x;
  long stride = 4096L * blockDim.x;
  const float4* w4 = (const float4*)w;
  char4* q4 = (char4*)q;
  for (; i < n4; i += stride) {
    float4 v = w4[i];
    char4 c;
    c.x = (char)(int)fminf(1.f, fmaxf(-1.f, rintf(v.x * scale)));
    c.y = (char)(int)fminf(1.f, fmaxf(-1.f, rintf(v.y * scale)));
    c.z = (char)(int)fminf(1.f, fmaxf(-1.f, rintf(v.z * scale)));
    c.w = (char)(int)fminf(1.f, fmaxf(-1.f, rintf(v.w * scale)));
    q4[i] = c;
  }
}

#define CORR_MAX 1024
#define WIN 1e-6f

__global__ __launch_bounds__(256) void quant_w_down(
    const float* __restrict__ w, const float* __restrict__ mean_ptr,
    char* __restrict__ q, int* __restrict__ cnt,
    int* __restrict__ ck, float* __restrict__ cv) {
  float scale = 1.0f / fmaxf(mean_ptr[2], 1e-5f);
  long i0 = ((long)blockIdx.x * blockDim.x + threadIdx.x) * 4;
  long stride = (long)gridDim.x * blockDim.x * 4;
  for (long i = i0; i < 4096L * 11008L; i += stride) {
    char4 c;
    #pragma unroll
    for (int j = 0; j < 4; j++) {
      float t = w[i + j] * scale;
      float qv = fminf(1.f, fmaxf(-1.f, rintf(t)));
      if (fabsf(fabsf(t) - 0.5f) < WIN) {
        qv = 0.f;
        int idx = atomicAdd(cnt, 1);
        if (idx < CORR_MAX) {
          ck[idx] = (int)(i + j);                 // flat n*11008+k
          cv[idx] = t > 0.f ? 0.5f : -0.5f;
        }
      }
      ((char*)&c)[j] = (char)(int)qv;
    }
    *(char4*)(q + i) = c;
  }
}

__global__ void zero_cnt(int* cnt) { *cnt = 0; }

__global__ __launch_bounds__(64) void apply_corr(
    const int* __restrict__ cnt, const int* __restrict__ ck,
    const float* __restrict__ cv, const char* __restrict__ qh,
    const float* __restrict__ fh, const float* __restrict__ meanw,
    float* __restrict__ out) {
  int r = blockIdx.x * 64 + threadIdx.x;  // 8192 rows
  float fwd = fmaxf(meanw[2], 1e-5f);
  int n = *cnt; if (n > CORR_MAX) n = CORR_MAX;
  float fr = fh[r] * fwd;
  for (int i = 0; i < n; i++) {
    int flat = ck[i];
    int nn = flat / 11008, kk = flat % 11008;
    float qv = (float)qh[(long)r * 11008 + kk];
    out[(long)r * 4096 + nn] += cv[i] * qv * fr;
  }
}

// ---------------------------------------------------------------- reductions
__device__ inline void block_reduce_sum_max_d(double& s, float& m) {
  #pragma unroll
  for (int off = 1; off < 64; off <<= 1) {
    s += __shfl_xor(s, off, 64);
    m = fmaxf(m, __shfl_xor(m, off, 64));
  }
  __shared__ double ssh[4];
  __shared__ float msh[4];
  int wv = threadIdx.x >> 6;
  if ((threadIdx.x & 63) == 0) { ssh[wv] = s; msh[wv] = m; }
  __syncthreads();
  s = (ssh[0] + ssh[1]) + (ssh[2] + ssh[3]);
  m = fmaxf(fmaxf(msh[0], msh[1]), fmaxf(msh[2], msh[3]));
}

// ------------------------------------------------------- activation quant
__device__ inline char quant1d(float x, double rn, double s) {
  double t = (double)x * rn;
  double q = rint(t * s);
  q = fmin(127.0, fmax(-128.0, q));
  return (char)(int)q;
}

__global__ __launch_bounds__(256) void act_quant_x(
    const float* __restrict__ x, char* __restrict__ qx, float* __restrict__ fx) {
  const int row = blockIdx.x;
  const float4* xr = (const float4*)(x + (long)row * 4096);
  float4 v[4];
  double ss = 0.0;
  float am = 0.f;
  #pragma unroll
  for (int i = 0; i < 4; i++) {
    v[i] = xr[i * 256 + threadIdx.x];
    ss += ((double)v[i].x * v[i].x + (double)v[i].y * v[i].y) +
          ((double)v[i].z * v[i].z + (double)v[i].w * v[i].w);
    am = fmaxf(am, fmaxf(fmaxf(fabsf(v[i].x), fabsf(v[i].y)),
                         fmaxf(fabsf(v[i].z), fabsf(v[i].w))));
  }
  block_reduce_sum_max_d(ss, am);
  double rn = 1.0 / sqrt(ss / 4096.0 + EPS);
  double den = fmax((double)am * rn, EPS);
  double s = 127.0 / den;
  if (threadIdx.x == 0) fx[row] = (float)(den / 127.0);
  char4* qr = (char4*)(qx + (long)row * 4096);
  #pragma unroll
  for (int i = 0; i < 4; i++) {
    char4 c;
    c.x = quant1d(v[i].x, rn, s);
    c.y = quant1d(v[i].y, rn, s);
    c.z = quant1d(v[i].z, rn, s);
    c.w = quant1d(v[i].w, rn, s);
    qr[i * 256 + threadIdx.x] = c;
  }
}

// h row cached in LDS (44KB) so the quant pass doesn't re-read 360MB from HBM.
__global__ __launch_bounds__(256) void act_quant_h(
    const float* __restrict__ h, char* __restrict__ qh, float* __restrict__ fh) {
  __shared__ float4 hrow4[2752];
  const long row = blockIdx.x;
  const float4* hr = (const float4*)(h + row * 11008);
  double ss = 0.0;
  float am = 0.f;
  for (int i = threadIdx.x; i < 2752; i += 256) {
    float4 v = hr[i];
    hrow4[i] = v;
    ss += ((double)v.x * v.x + (double)v.y * v.y) +
          ((double)v.z * v.z + (double)v.w * v.w);
    am = fmaxf(am, fmaxf(fmaxf(fabsf(v.x), fabsf(v.y)),
                         fmaxf(fabsf(v.z), fabsf(v.w))));
  }
  block_reduce_sum_max_d(ss, am);   // contains __syncthreads (covers hrow4)
  double rn = 1.0 / sqrt(ss / 11008.0 + EPS);
  double den = fmax((double)am * rn, EPS);
  double s = 127.0 / den;
  if (threadIdx.x == 0) fh[row] = (float)(den / 127.0);
  char4* qr = (char4*)(qh + row * 11008);
  for (int i = threadIdx.x; i < 2752; i += 256) {
    float4 v = hrow4[i];
    char4 c;
    c.x = quant1d(v.x, rn, s);
    c.y = quant1d(v.y, rn, s);
    c.z = quant1d(v.z, rn, s);
    c.w = quant1d(v.w, rn, s);
    qr[i] = c;
  }
}

// =============================================================================
// GEMMs: mfma_i32_16x16x64_i8 with the r9 PMC-verified conflict-free rotation
// swizzle. REGISTER-DOUBLE-BUFFERED dep-break K-loop: iteration ks reads
// frags(ks+1) into the *other* named reg set while MFMA consumes frags(ks) —
// no intra-iteration read->MFMA dependency, so LDS latency hides under MFMA.
// Stage distance 3 (prologue stages 0,1,2), 3 LDS buffers by pointer rotation,
// counted vmcnt(6) at iteration end (stage ks+2 landed; ks+3 stays in flight).
// Explicit 2x-unrolled loop with named reg sets (no runtime-indexed frags).
//   gateup: 128x128, 4 waves (2x2 of 64x64), 72KB LDS -> 2 blocks/CU.
//   down:   128x256, 4 waves (2m x 2n of 64x128), 72KB LDS -> 2 blocks/CU.
// XCD-bijective swizzle, m-fastest (B panels L2-hot).
// =============================================================================

__global__ __launch_bounds__(256, 2) void gemm_gateup(
    const char* __restrict__ qx, const char* __restrict__ qwg, const char* __restrict__ qwu,
    const float* __restrict__ meanw, const float* __restrict__ fx, float* __restrict__ h) {
  __shared__ __align__(16) char As[3][8192];
  __shared__ __align__(16) char Bgs[3][8192];
  __shared__ __align__(16) char Bus[3][8192];
  const int t = threadIdx.x;
  const int lane = t & 63;
  const int wv = t >> 6;                       // 0..3
  const int bid = blockIdx.x;                  // 5504 = 8 * 688
  const int swz = (bid & 7) * 688 + (bid >> 3);
  const int m0 = (swz & 63) * 128;
  const int n0 = (swz >> 6) * 128;
  const int wm = (wv >> 1) * 64;
  const int wn = (wv & 1) * 64;

  const int rowin = lane >> 2;
  const int gcol = (((lane & 3) - ((lane >> 3) & 3)) & 3) * 16;
  const int loff = (lane & 15) * 64 + ((((lane >> 4) + ((lane >> 1) & 3)) & 3) << 4);

  const char* gA = qx  + (long)(m0 + wv * 32 + rowin) * 4096 + gcol;
  const char* gG = qwg + (long)(n0 + wv * 32 + rowin) * 4096 + gcol;
  const char* gU = qwu + (long)(n0 + wv * 32 + rowin) * 4096 + gcol;
  const long R16 = 16L * 4096;

  int32x4 accg[4][4] = {};
  int32x4 accu[4][4] = {};
  int32x4 a0[4], g0[4], u0[4], a1[4], g1[4], u1[4];

  char *PA0 = &As[0][0], *PA1 = &As[1][0], *PA2 = &As[2][0];
  char *PG0 = &Bgs[0][0], *PG1 = &Bgs[1][0], *PG2 = &Bgs[2][0];
  char *PU0 = &Bus[0][0], *PU1 = &Bus[1][0], *PU2 = &Bus[2][0];

  #define GU_STAGE(pa, pg, pu, k0)                          \
    do {                                                    \
      gload(gA + (k0),       (pa) + wv * 2048);             \
      gload(gA + (k0) + R16, (pa) + wv * 2048 + 1024);      \
      gload(gG + (k0),       (pg) + wv * 2048);             \
      gload(gG + (k0) + R16, (pg) + wv * 2048 + 1024);      \
      gload(gU + (k0),       (pu) + wv * 2048);             \
      gload(gU + (k0) + R16, (pu) + wv * 2048 + 1024);      \
    } while (0)

  #define GU_READ(ar, gr, ur, pa, pg, pu)                          \
    do {                                                           \
      _Pragma("unroll")                                            \
      for (int m = 0; m < 4; m++)                                  \
        ar[m] = *(const int32x4*)((pa) + (wm + m * 16) * 64 + loff); \
      _Pragma("unroll")                                            \
      for (int n = 0; n < 4; n++) {                                \
        gr[n] = *(const int32x4*)((pg) + (wn + n * 16) * 64 + loff); \
        ur[n] = *(const int32x4*)((pu) + (wn + n * 16) * 64 + loff); \
      }                                                            \
    } while (0)

  #define GU_MFMA(ar, gr, ur)                                                \
    do {                                                                     \
      __builtin_amdgcn_s_setprio(1);                                         \
      _Pragma("unroll")                                                      \
      for (int n = 0; n < 4; n++) {                                          \
        _Pragma("unroll")                                                    \
        for (int m = 0; m < 4; m++) {                                        \
          accg[m][n] = __builtin_amdgcn_mfma_i32_16x16x64_i8(ar[m], gr[n], accg[m][n], 0, 0, 0); \
          accu[m][n] = __builtin_amdgcn_mfma_i32_16x16x64_i8(ar[m], ur[n], accu[m][n], 0, 0, 0); \
        }                                                                    \
      }                                                                      \
      __builtin_amdgcn_s_setprio(0);                                         \
    } while (0)

  #define GU_ROT()                                          \
    do {                                                    \
      char* tp;                                             \
      tp = PA0; PA0 = PA1; PA1 = PA2; PA2 = tp;             \
      tp = PG0; PG0 = PG1; PG1 = PG2; PG2 = tp;             \
      tp = PU0; PU0 = PU1; PU1 = PU2; PU2 = tp;             \
    } while (0)

  #define GU_BODY(ks, Rc_a, Rc_g, Rc_u, Rn_a, Rn_g, Rn_u)          \
    do {                                                           \
      if ((ks) + 3 < 64) GU_STAGE(PA0, PG0, PU0, ((ks) + 3) * 64); \
      if ((ks) + 1 < 64) GU_READ(Rn_a, Rn_g, Rn_u, PA1, PG1, PU1); \
      GU_MFMA(Rc_a, Rc_g, Rc_u);                                   \
      if ((ks) + 3 < 64) asm volatile("s_waitcnt vmcnt(6)" ::: "memory"); \
      else               asm volatile("s_waitcnt vmcnt(0)" ::: "memory"); \
      if ((ks) < 62) __builtin_amdgcn_s_barrier();                 \
      GU_ROT();                                                    \
    } while (0)

  // prologue: stages 0,1,2; frags(0) -> set0; validate stage1.
  GU_STAGE(PA0, PG0, PU0, 0);
  GU_STAGE(PA1, PG1, PU1, 64);
  GU_STAGE(PA2, PG2, PU2, 128);
  asm volatile("s_waitcnt vmcnt(12)" ::: "memory");
  __builtin_amdgcn_s_barrier();
  GU_READ(a0, g0, u0, PA0, PG0, PU0);
  asm volatile("s_waitcnt vmcnt(6)" ::: "memory");
  __builtin_amdgcn_s_barrier();

  for (int ks = 0; ks < 64; ks += 2) {
    GU_BODY(ks,     a0, g0, u0, a1, g1, u1);
    GU_BODY(ks + 1, a1, g1, u1, a0, g0, u0);
  }
  #undef GU_STAGE
  #undef GU_READ
  #undef GU_MFMA
  #undef GU_ROT
  #undef GU_BODY

  float fwg = fmaxf(meanw[0], 1e-5f);
  float fwu = fmaxf(meanw[1], 1e-5f);
  const int rgrp = lane >> 4;
  const int cidx = lane & 15;
  #pragma unroll
  for (int m = 0; m < 4; m++) {
    #pragma unroll
    for (int r = 0; r < 4; r++) {
      int grow = m0 + wm + m * 16 + rgrp * 4 + r;
      float fxr = fx[grow];
      float sg = fxr * fwg, su = fxr * fwu;
      #pragma unroll
      for (int n = 0; n < 4; n++) {
        float g = (float)accg[m][n][r] * sg;
        float u = (float)accu[m][n][r] * su;
        float hv = g / (1.f + expf(-g)) * u;
        h[(long)grow * 11008 + (n0 + wn + n * 16 + cidx)] = hv;
      }
    }
  }
}

__global__ __launch_bounds__(256, 2) void gemm_down(
    const char* __restrict__ qh, const char* __restrict__ qwd,
    const float* __restrict__ meanw, const float* __restrict__ fh,
    float* __restrict__ out) {
  __shared__ __align__(16) char As[3][8192];
  __shared__ __align__(16) char Bs[3][16384];
  const int t = threadIdx.x;
  const int lane = t & 63;
  const int wv = t >> 6;
  const int bid = blockIdx.x;                  // 1024 = 8 * 128
  const int swz = (bid & 7) * 128 + (bid >> 3);
  const int m0 = (swz & 63) * 128;
  const int n0 = (swz >> 6) * 256;
  const int wm = (wv >> 1) * 64;
  const int wn = (wv & 1) * 128;

  const int rowin = lane >> 2;
  const int gcol = (((lane & 3) - ((lane >> 3) & 3)) & 3) * 16;
  const int loff = (lane & 15) * 64 + ((((lane >> 4) + ((lane >> 1) & 3)) & 3) << 4);

  const char* gA = qh  + (long)(m0 + wv * 32 + rowin) * 11008 + gcol;
  const char* gB = qwd + (long)(n0 + wv * 64 + rowin) * 11008 + gcol;
  const long R16 = 16L * 11008;

  int32x4 acc[4][8] = {};
  int32x4 a0[4], b0[8], a1[4], b1[8];

  char *PA0 = &As[0][0], *PA1 = &As[1][0], *PA2 = &As[2][0];
  char *PB0 = &Bs[0][0], *PB1 = &Bs[1][0], *PB2 = &Bs[2][0];

  #define DN_STAGE(pa, pb, k0)                              \
    do {                                                    \
      gload(gA + (k0),           (pa) + wv * 2048);         \
      gload(gA + (k0) + R16,     (pa) + wv * 2048 + 1024);  \
      gload(gB + (k0),           (pb) + wv * 4096);         \
      gload(gB + (k0) + R16,     (pb) + wv * 4096 + 1024);  \
      gload(gB + (k0) + 2 * R16, (pb) + wv * 4096 + 2048);  \
      gload(gB + (k0) + 3 * R16, (pb) + wv * 4096 + 3072);  \
    } while (0)

  #define DN_READ(ar, br, pa, pb)                                   \
    do {                                                            \
      _Pragma("unroll")                                             \
      for (int m = 0; m < 4; m++)                                   \
        ar[m] = *(const int32x4*)((pa) + (wm + m * 16) * 64 + loff);\
      _Pragma("unroll")                                             \
      for (int n = 0; n < 8; n++)                                   \
        br[n] = *(const int32x4*)((pb) + (wn + n * 16) * 64 + loff);\
    } while (0)

  #define DN_MFMA(ar, br)                                                    \
    do {                                                                     \
      __builtin_amdgcn_s_setprio(1);                                         \
      _Pragma("unroll")                                                      \
      for (int n = 0; n < 8; n++) {                                          \
        _Pragma("unroll")                                                    \
        for (int m = 0; m < 4; m++)                                          \
          acc[m][n] = __builtin_amdgcn_mfma_i32_16x16x64_i8(ar[m], br[n], acc[m][n], 0, 0, 0); \
      }                                                                      \
      __builtin_amdgcn_s_setprio(0);                                         \
    } while (0)

  #define DN_ROT()                                          \
    do {                                                    \
      char* tp;                                             \
      tp = PA0; PA0 = PA1; PA1 = PA2; PA2 = tp;             \
      tp = PB0; PB0 = PB1; PB1 = PB2; PB2 = tp;             \
    } while (0)

  #define DN_BODY(ks, Rc_a, Rc_b, Rn_a, Rn_b)                      \
    do {                                                           \
      if ((ks) + 3 < 172) DN_STAGE(PA0, PB0, ((ks) + 3) * 64);     \
      if ((ks) + 1 < 172) DN_READ(Rn_a, Rn_b, PA1, PB1);           \
      DN_MFMA(Rc_a, Rc_b);                                         \
      if ((ks) + 3 < 172) asm volatile("s_waitcnt vmcnt(6)" ::: "memory"); \
      else                asm volatile("s_waitcnt vmcnt(0)" ::: "memory"); \
      if ((ks) < 170) __builtin_amdgcn_s_barrier();                \
      DN_ROT();                                                    \
    } while (0)

  DN_STAGE(PA0, PB0, 0);
  DN_STAGE(PA1, PB1, 64);
  DN_STAGE(PA2, PB2, 128);
  asm volatile("s_waitcnt vmcnt(12)" ::: "memory");
  __builtin_amdgcn_s_barrier();
  DN_READ(a0, b0, PA0, PB0);
  asm volatile("s_waitcnt vmcnt(6)" ::: "memory");
  __builtin_amdgcn_s_barrier();

  for (int ks = 0; ks < 172; ks += 2) {
    DN_BODY(ks,     a0, b0, a1, b1);
    DN_BODY(ks + 1, a1, b1, a0, b0);
  }
  #undef DN_STAGE
  #undef DN_READ
  #undef DN_MFMA
  #undef DN_ROT
  #undef DN_BODY

  float fwd = fmaxf(meanw[2], 1e-5f);
  const int rgrp = lane >> 4;
  const int cidx = lane & 15;
  #pragma unroll
  for (int m = 0; m < 4; m++) {
    #pragma unroll
    for (int r = 0; r < 4; r++) {
      int grow = m0 + wm + m * 16 + rgrp * 4 + r;
      float f = fh[grow] * fwd;
      #pragma unroll
      for (int n = 0; n < 8; n++) {
        out[(long)grow * 4096 + (n0 + wn + n * 16 + cidx)] =
            (float)acc[m][n][r] * f;
      }
    }
  }
}

// ---------------------------------------------------------------- launch
extern "C" void kernel_launch(void* const* d_in, const int* in_sizes, int n_in,
                              void* d_out, int out_size, void* d_ws, size_t ws_size,
                              hipStream_t stream) {
  const float* x      = (const float*)d_in[0];
  const float* w_gate = (const float*)d_in[1];
  const float* w_up   = (const float*)d_in[2];
  const float* w_down = (const float*)d_in[3];
  float* out = (float*)d_out;

  const long NW = 11008L * 4096L;     // 45088768 per weight
  const long NX = 8192L * 4096L;      // 33554432
  const long NH = 8192L * 11008L;     // 90177536

  char* ws  = (char*)d_ws;
  char* qwg = ws;
  char* qwu = qwg + NW;
  char* qwd = qwu + NW;
  char* qx  = qwd + NW;
  char* qh  = qx + NX;
  float* h  = (float*)(qh + NH);
  float* fx = h + NH;                 // 8192 floats
  float* fh = fx + 8192;              // 8192 floats
  float* meanw = fh + 8192;           // [0]=gate [1]=up [2]=down (+pad)
  float* bs    = meanw + 4;           // 3*131072 floats
  float* part  = bs + 3 * 131072;     // 3*256 floats
  int*   ccnt  = (int*)(part + 1024);
  int*   ck    = ccnt + 4;            // CORR_MAX ints
  float* cv    = (float*)(ck + CORR_MAX);

  zero_cnt<<<1, 1, 0, stream>>>(ccnt);

  // numpy-style fp32 pairwise means, all three matrices fused per level
  np_blocksums3<<<1536, 256, 0, stream>>>(w_gate, w_up, w_down, bs);
  np_tree_partial3<<<768, 256, 0, stream>>>(bs, part);
  np_tree_final3<<<3, 128, 0, stream>>>(part, meanw);

  quant_w_gu<<<8192, 256, 0, stream>>>(w_gate, w_up, meanw, qwg, qwu, NW / 4);
  quant_w_down<<<4096, 256, 0, stream>>>(w_down, meanw, qwd, ccnt, ck, cv);

  act_quant_x<<<8192, 256, 0, stream>>>(x, qx, fx);

  gemm_gateup<<<5504, 256, 0, stream>>>(qx, qwg, qwu, meanw, fx, h);

  act_quant_h<<<8192, 256, 0, stream>>>(h, qh, fh);

  gemm_down<<<1024, 256, 0, stream>>>(qh, qwd, meanw, fh, out);

  apply_corr<<<128, 64, 0, stream>>>(ccnt, ck, cv, qh, fh, meanw, out);
}